// Round 10
// baseline (112.022 us; speedup 1.0000x reference)
//
#include <hip/hip_runtime.h>
#include <math.h>

#define TB   256
#define HH   128     // input H=W
#define OHW  64      // output H=W
#define TR   16      // output rows per tile
#define NT   4       // tiles per plane
#define XR   37      // slab rows: 2*TR+5

__device__ __forceinline__ float sigmoidf(float z) {
    return 1.0f / (1.0f + __expf(-z));
}

__device__ __forceinline__ void gl2lds16(const float* g, float* l) {
    __builtin_amdgcn_global_load_lds(
        (const __attribute__((address_space(1))) void*)g,
        (__attribute__((address_space(3))) void*)l, 16, 0, 0);
}
__device__ __forceinline__ void gl2lds4(const float* g, float* l) {
    __builtin_amdgcn_global_load_lds(
        (const __attribute__((address_space(1))) void*)g,
        (__attribute__((address_space(3))) void*)l, 4, 0, 0);
}

// One block = one 16-row tile of one plane. Wave w owns output rows 4w..4w+3
// and redundantly computes n0 for rows 4w-1 and 4w+4 (3 convs each) so that
// stage 2 needs NO LDS n0 exchange and NO second barrier. One col per lane.
__global__ __launch_bounds__(TB, 8) void fused_densenet_kernel(
    const float* __restrict__ x,
    const float* __restrict__ maxgate,
    const float* __restrict__ mb,
    const float* __restrict__ pconvs,
    const float* __restrict__ pbs,
    const float* __restrict__ pgates,
    const float* __restrict__ gbs,
    float* __restrict__ out)
{
    __shared__ float xs[XR][HH];        // contiguous slab, 18.5 KB -> 8 blocks/CU

    const int t     = threadIdx.x;
    const int lane  = t & 63;           // output col
    const int wv    = t >> 6;           // wave 0..3
    const int bid   = blockIdx.x;
    const int tile  = bid & 3;
    const int plane = bid >> 2;         // b*256 + c
    const int c     = plane & 255;
    const int r0    = tile * TR;

    // ---- weights/biases (block-uniform address -> scalar-resident) ----
    // ws rows: 0=maxgate 1=p0 2=p1 3=p2 4=p3 5=gate0 6=gate2(leaf1+node)
    float ws[7][9];
#pragma unroll
    for (int i = 0; i < 9; ++i) {
        ws[0][i] = maxgate[c * 9  + i];
        ws[1][i] = pconvs [c * 36 + i * 4 + 0];
        ws[2][i] = pconvs [c * 36 + i * 4 + 1];
        ws[3][i] = pconvs [c * 36 + i * 4 + 2];
        ws[4][i] = pconvs [c * 36 + i * 4 + 3];
        ws[5][i] = pgates [c * 27 + i * 3 + 0];
        ws[6][i] = pgates [c * 27 + i * 3 + 2];
    }
    const float bmax = mb[c];
    const float bp0 = pbs[c * 4 + 0], bp1 = pbs[c * 4 + 1];
    const float bp2 = pbs[c * 4 + 2], bp3 = pbs[c * 4 + 3];
    const float bg0 = gbs[c * 3 + 0];   // leaf0 gate bias
    const float bg1 = gbs[c * 3 + 1];   // leaf1 gate bias
    const float bg2 = gbs[c * 3 + 2];   // node gate bias

    const float* xplane = x + (size_t)plane * (HH * HH);

    // ---- async stage: input rows 2r0-3 .. 2r0+33, zero-padded at image edges ----
    {
        const int ir0  = 2 * r0 - 3;
        const int lo   = ir0 < 0 ? 0 : ir0;
        const int hie  = ir0 + XR - 1;
        const int hi   = hie > HH - 1 ? HH - 1 : hie;
        const int ztop = lo - ir0;                 // 0 or 3
        const int zbot = hie - hi;                 // 0 or 2
        for (int i = t; i < ztop * HH; i += TB) xs[0][i] = 0.f;
        for (int i = t; i < zbot * HH; i += TB) (&xs[XR - zbot][0])[i] = 0.f;
        const int    nfl  = (hi - lo + 1) * HH;    // multiple of 128
        const float* gsrc = xplane + lo * HH;
        float*       ldst = &xs[ztop][0];
        const int nchunk = nfl >> 8;               // 1KB chunks
        for (int k = wv; k < nchunk; k += TB / 64)
            gl2lds16(gsrc + (k << 8) + lane * 4, ldst + (k << 8));
        if ((nfl & 255) && wv == 0) {              // 512B tail
            const int off = nchunk << 8;
            gl2lds4(gsrc + off + lane,      ldst + off);
            gl2lds4(gsrc + off + 64 + lane, ldst + off + 64);
        }
    }
    __syncthreads();    // drains vmcnt: slab ready; the ONLY barrier

    const int cc = lane;
    float* op = out + (size_t)plane * (OHW * OHW);

    float a0, ax, ay, b0, bx, by, c0, cx, cy;     // rolling 3-row window

// load window row: cols 2cc-1 (0 at left edge), 2cc, 2cc+1
#define LDW(XRW, V0, VX, VY) {                                                  \
        const float* _r = &xs[(XRW)][0];                                        \
        const float2 _d = *reinterpret_cast<const float2*>(&_r[2 * cc]);        \
        float _v = _r[cc ? 2 * cc - 1 : 0];                                     \
        V0 = cc ? _v : 0.f; VX = _d.x; VY = _d.y; }

// n0-only: convs p0, p1, gate0
#define N0ONLY(N0) {                                                            \
        const float _ag = a0*ws[5][0]+ax*ws[5][1]+ay*ws[5][2]                   \
                        + b0*ws[5][3]+bx*ws[5][4]+by*ws[5][5]                   \
                        + c0*ws[5][6]+cx*ws[5][7]+cy*ws[5][8];                  \
        const float _q0 = a0*ws[1][0]+ax*ws[1][1]+ay*ws[1][2]                   \
                        + b0*ws[1][3]+bx*ws[1][4]+by*ws[1][5]                   \
                        + c0*ws[1][6]+cx*ws[1][7]+cy*ws[1][8];                  \
        const float _q1 = a0*ws[2][0]+ax*ws[2][1]+ay*ws[2][2]                   \
                        + b0*ws[2][3]+bx*ws[2][4]+by*ws[2][5]                   \
                        + c0*ws[2][6]+cx*ws[2][7]+cy*ws[2][8];                  \
        const float _sg = sigmoidf(_ag + bg0);                                  \
        N0 = _sg * (_q0 + bp0) + (1.f - _sg) * (_q1 + bp1); }

// full stage-1: 7 convs + maxpool at output row GR
#define STG1(GR, N0, O1, N1P) {                                                 \
        N0ONLY(N0)                                                              \
        const float _am = a0*ws[0][0]+ax*ws[0][1]+ay*ws[0][2]                   \
                        + b0*ws[0][3]+bx*ws[0][4]+by*ws[0][5]                   \
                        + c0*ws[0][6]+cx*ws[0][7]+cy*ws[0][8];                  \
        const float _q2 = a0*ws[3][0]+ax*ws[3][1]+ay*ws[3][2]                   \
                        + b0*ws[3][3]+bx*ws[3][4]+by*ws[3][5]                   \
                        + c0*ws[3][6]+cx*ws[3][7]+cy*ws[3][8];                  \
        const float _q3 = a0*ws[4][0]+ax*ws[4][1]+ay*ws[4][2]                   \
                        + b0*ws[4][3]+bx*ws[4][4]+by*ws[4][5]                   \
                        + c0*ws[4][6]+cx*ws[4][7]+cy*ws[4][8];                  \
        const float _g2 = a0*ws[6][0]+ax*ws[6][1]+ay*ws[6][2]                   \
                        + b0*ws[6][3]+bx*ws[6][4]+by*ws[6][5]                   \
                        + c0*ws[6][6]+cx*ws[6][7]+cy*ws[6][8];                  \
        const float _hA = fmaxf(fmaxf(cc ? a0 : -INFINITY, ax), ay);            \
        const float _hB = fmaxf(fmaxf(cc ? b0 : -INFINITY, bx), by);            \
        const float _hC = fmaxf(fmaxf(cc ? c0 : -INFINITY, cx), cy);            \
        const float _mp = fmaxf(fmaxf((GR) > 0 ? _hA : -INFINITY, _hB), _hC);   \
        O1 = _mp * (_am + bmax);                                                \
        const float _s1 = sigmoidf(_g2 + bg1);  /* leaf1 gate: bias gbs[:,1] */ \
        N1P = _s1 * (_q2 + bp2) + (1.f - _s1) * (_q3 + bp3); }

// horizontal n0 halos (cols 0/63 are true image edges -> 0)
#define HALO(V, L, R) {                                                         \
        const float _u = __shfl_up(V, 1);   L = cc ? _u : 0.f;                  \
        const float _d = __shfl_down(V, 1); R = (cc < 63) ? _d : 0.f; }

// stage-2 emit of output row GRE
#define EMIT(GRE, O1, N1P) {                                                    \
        const float _ag = ppl*ws[6][0] + pp *ws[6][1] + ppr*ws[6][2]            \
                        + pvl*ws[6][3] + pv *ws[6][4] + pvr*ws[6][5]            \
                        + cul*ws[6][6] + cu *ws[6][7] + cur_*ws[6][8];          \
        const float _g = sigmoidf(_ag + bg2);   /* node gate: bias gbs[:,2] */  \
        __builtin_nontemporal_store((O1) + pv * _g + (N1P) * (1.f - _g),        \
                                    op + (GRE) * OHW + cc); }

    const int xb = 8 * wv;             // wave's base slab row

    // j=0: extra top row (lr = 4wv-1)
    LDW(xb,     a0, ax, ay);
    LDW(xb + 1, b0, bx, by);
    LDW(xb + 2, c0, cx, cy);
    float pp, ppl, ppr;
    {
        const int gr = r0 + 4 * wv - 1;
        float n0v; N0ONLY(n0v);
        pp = ((unsigned)gr < (unsigned)OHW) ? n0v : 0.f;
        HALO(pp, ppl, ppr);
    }

    // j=1: first own row (lr = 4wv) — nothing to emit yet
    float pv, pvl, pvr, po1, pn1;
    {
        a0 = c0; ax = cx; ay = cy;
        LDW(xb + 3, b0, bx, by);
        LDW(xb + 4, c0, cx, cy);
        const int gr = r0 + 4 * wv;
        STG1(gr, pv, po1, pn1);
        HALO(pv, pvl, pvr);
    }

    // j=2..4: own rows, emit row lr-1
#pragma unroll
    for (int j = 2; j <= 4; ++j) {
        a0 = c0; ax = cx; ay = cy;
        LDW(xb + 2 * j + 1, b0, bx, by);
        LDW(xb + 2 * j + 2, c0, cx, cy);
        const int gr = r0 + 4 * wv - 1 + j;
        float cu, cul, cur_, o1, n1p;
        STG1(gr, cu, o1, n1p);
        HALO(cu, cul, cur_);
        EMIT(gr - 1, po1, pn1);
        pp = pv; ppl = pvl; ppr = pvr;
        pv = cu; pvl = cul; pvr = cur_;
        po1 = o1; pn1 = n1p;
    }

    // j=5: extra bottom row (lr = 4wv+4), emit last own row (4wv+3)
    {
        a0 = c0; ax = cx; ay = cy;
        LDW(xb + 11, b0, bx, by);
        LDW(xb + 12, c0, cx, cy);
        const int gr = r0 + 4 * wv + 4;
        float cu; N0ONLY(cu);
        cu = ((unsigned)gr < (unsigned)OHW) ? cu : 0.f;
        float cul, cur_;
        HALO(cu, cul, cur_);
        EMIT(gr - 1, po1, pn1);
    }
#undef LDW
#undef N0ONLY
#undef STG1
#undef HALO
#undef EMIT
}

extern "C" void kernel_launch(void* const* d_in, const int* in_sizes, int n_in,
                              void* d_out, int out_size, void* d_ws, size_t ws_size,
                              hipStream_t stream) {
    const float* x       = (const float*)d_in[0];
    const float* maxgate = (const float*)d_in[1];
    const float* mb      = (const float*)d_in[2];
    const float* pconvs  = (const float*)d_in[3];
    const float* pbs     = (const float*)d_in[4];
    const float* pgates  = (const float*)d_in[5];
    const float* gbs     = (const float*)d_in[6];
    float* out           = (float*)d_out;

    const int blocks = 16 * 256 * NT;   // one 16-row tile per block
    fused_densenet_kernel<<<blocks, TB, 0, stream>>>(
        x, maxgate, mb, pconvs, pbs, pgates, gbs, out);
}

// Round 11
// 81.633 us; speedup vs baseline: 1.3723x; 1.3723x over previous
//
#include <hip/hip_runtime.h>
#include <math.h>

#define TB   256
#define HH   128     // input H=W
#define OHW  64      // output H=W
#define TR   16      // output rows per tile (4 tiles/plane)
#define XR   37      // slab rows: 2*TR+5
#define N0C  68      // n0 row stride; out col c at index c+2

typedef float f32x2 __attribute__((ext_vector_type(2)));

__device__ __forceinline__ float sigmoidf(float z) {
    return 1.0f / (1.0f + __expf(-z));
}

__device__ __forceinline__ void gl2lds16(const float* g, float* l) {
    __builtin_amdgcn_global_load_lds(
        (const __attribute__((address_space(1))) void*)g,
        (__attribute__((address_space(3))) void*)l, 16, 0, 0);
}
__device__ __forceinline__ void gl2lds4(const float* g, float* l) {
    __builtin_amdgcn_global_load_lds(
        (const __attribute__((address_space(1))) void*)g,
        (__attribute__((address_space(3))) void*)l, 4, 0, 0);
}

// One block = one 16-row tile. 23.3 KB LDS -> 6 blocks/CU so the CU scheduler
// can interleave different blocks' stage (async gl_lds) and compute phases.
__global__ __launch_bounds__(TB, 6) void fused_densenet_kernel(
    const float* __restrict__ x,
    const float* __restrict__ maxgate,
    const float* __restrict__ mb,
    const float* __restrict__ pconvs,
    const float* __restrict__ pbs,
    const float* __restrict__ pgates,
    const float* __restrict__ gbs,
    float* __restrict__ out)
{
    __shared__ float xs[XR][HH];          // contiguous slab (18.5 KB)
    __shared__ float n0s[TR + 2][N0C];    // n0 with 1-halo (4.9 KB)

    const int t     = threadIdx.x;
    const int lane  = t & 63;
    const int wv    = t >> 6;             // wave 0..3
    const int bid   = blockIdx.x;
    const int tile  = bid & 3;
    const int plane = bid >> 2;           // b*256 + c
    const int c     = plane & 255;
    const int r0    = tile * TR;

    // ---- weights/biases (block-uniform address -> scalar-resident) ----
    // ws rows: 0=maxgate 1=p0 2=p1 3=p2 4=p3 5=gate0 6=gate2(leaf1+node)
    float ws[7][9];
#pragma unroll
    for (int i = 0; i < 9; ++i) {
        ws[0][i] = maxgate[c * 9  + i];
        ws[1][i] = pconvs [c * 36 + i * 4 + 0];
        ws[2][i] = pconvs [c * 36 + i * 4 + 1];
        ws[3][i] = pconvs [c * 36 + i * 4 + 2];
        ws[4][i] = pconvs [c * 36 + i * 4 + 3];
        ws[5][i] = pgates [c * 27 + i * 3 + 0];
        ws[6][i] = pgates [c * 27 + i * 3 + 2];
    }
    const float bmax = mb[c];
    const float bp0 = pbs[c * 4 + 0], bp1 = pbs[c * 4 + 1];
    const float bp2 = pbs[c * 4 + 2], bp3 = pbs[c * 4 + 3];
    const float bg0 = gbs[c * 3 + 0];   // leaf0 gate bias
    const float bg1 = gbs[c * 3 + 1];   // leaf1 gate bias
    const float bg2 = gbs[c * 3 + 2];   // node gate bias

    const float* xplane = x + (size_t)plane * (HH * HH);

    // ---- async stage: input rows 2r0-3 .. 2r0+33 into xs, zero-pad at edges ----
    {
        const int ir0  = 2 * r0 - 3;
        const int lo   = ir0 < 0 ? 0 : ir0;
        const int hie  = ir0 + XR - 1;
        const int hi   = hie > HH - 1 ? HH - 1 : hie;
        const int ztop = lo - ir0;                 // 3 for tile 0, else 0
        const int zbot = hie - hi;                 // 2 for tile 3, else 0
        for (int i = t; i < ztop * HH; i += TB) (&xs[0][0])[i] = 0.f;
        for (int i = t; i < zbot * HH; i += TB) (&xs[XR - zbot][0])[i] = 0.f;
        const int    nfl  = (hi - lo + 1) * HH;    // multiple of 128
        const float* gsrc = xplane + lo * HH;
        float*       ldst = &xs[ztop][0];
        const int nchunk = nfl >> 8;               // 1KB chunks (64 lanes x 16B)
        for (int k = wv; k < nchunk; k += TB / 64)
            gl2lds16(gsrc + (k << 8) + lane * 4, ldst + (k << 8));
        if ((nfl & 255) && wv == 0) {              // 512B tail
            const int off = nchunk << 8;
            gl2lds4(gsrc + off + lane,      ldst + off);
            gl2lds4(gsrc + off + 64 + lane, ldst + off + 64);
        }
        // n0 side cols (gc = -1 and 64) are outside the image -> always 0
        if (t < 2 * (TR + 2)) n0s[t >> 1][(t & 1) ? 66 : 1] = 0.f;
    }
    __syncthreads();                               // slab + side zeros ready

    // ---- n0 halo rows (gr = r0-1, r0+TR; zero outside image) ----
    if (t < 132) {
        const int hb  = (t >= 66);                 // 0 top, 1 bottom
        const int cc2 = hb ? t - 66 : t;           // 0..65
        const int gc  = cc2 - 1;                   // out col -1..64
        const int gr  = hb ? r0 + TR : r0 - 1;
        float n0v = 0.f;
        if ((unsigned)gr < (unsigned)OHW && (unsigned)gc < (unsigned)OHW) {
            const int sb = hb ? 2 * TR + 2 : 0;    // slab row base
            float ag = 0.f, a0 = 0.f, a1 = 0.f;
#pragma unroll
            for (int dr = 0; dr < 3; ++dr) {
                const float* row = &xs[sb + dr][0];
                const float w0 = (gc > 0) ? row[2 * gc - 1] : 0.f;
                const float w1 = row[2 * gc];
                const float w2 = row[2 * gc + 1];
                ag += w0 * ws[5][3*dr] + w1 * ws[5][3*dr+1] + w2 * ws[5][3*dr+2];
                a0 += w0 * ws[1][3*dr] + w1 * ws[1][3*dr+1] + w2 * ws[1][3*dr+2];
                a1 += w0 * ws[2][3*dr] + w1 * ws[2][3*dr+1] + w2 * ws[2][3*dr+2];
            }
            const float sg = sigmoidf(ag + bg0);
            n0v = sg * (a0 + bp0) + (1.f - sg) * (a1 + bp1);
        }
        n0s[hb ? TR + 1 : 0][cc2 + 1] = n0v;
    }

    // ---- stage 1 interior: 2 cols x 1 row per micro-step, rows g0 & g0+8 ----
    const int p  = t & 31;             // col pair: out cols {2p, 2p+1}
    const int g0 = t >> 5;             // 0..7
    float out1[2][2], n1v[2][2];

#pragma unroll
    for (int k = 0; k < 2; ++k) {
        const int lr = g0 + 8 * k;
        const int gr = r0 + lr;
        float a[7][2];
#pragma unroll
        for (int ci = 0; ci < 7; ++ci) { a[ci][0] = 0.f; a[ci][1] = 0.f; }
        float mp0 = -INFINITY, mp1 = -INFINITY;
#pragma unroll
        for (int dr = 0; dr < 3; ++dr) {
            const float* row = &xs[2 * lr + 2 + dr][0];
            const float  v0 = (p > 0) ? row[4 * p - 1] : 0.f;
            const float4 vv = *reinterpret_cast<const float4*>(&row[4 * p]);
            const bool rowok = (gr > 0) | (dr > 0);
            const float h0 = fmaxf(fmaxf((p > 0) ? v0 : -INFINITY, vv.x), vv.y);
            const float h1 = fmaxf(fmaxf(vv.y, vv.z), vv.w);
            mp0 = fmaxf(mp0, rowok ? h0 : -INFINITY);
            mp1 = fmaxf(mp1, rowok ? h1 : -INFINITY);
#pragma unroll
            for (int ci = 0; ci < 7; ++ci) {
                a[ci][0] += v0   * ws[ci][3*dr] + vv.x * ws[ci][3*dr+1] + vv.y * ws[ci][3*dr+2];
                a[ci][1] += vv.y * ws[ci][3*dr] + vv.z * ws[ci][3*dr+1] + vv.w * ws[ci][3*dr+2];
            }
        }
        const float sg0a = sigmoidf(a[5][0] + bg0);
        const float sg0b = sigmoidf(a[5][1] + bg0);
        const float n0a = sg0a * (a[1][0] + bp0) + (1.f - sg0a) * (a[2][0] + bp1);
        const float n0b = sg0b * (a[1][1] + bp0) + (1.f - sg0b) * (a[2][1] + bp1);
        *reinterpret_cast<f32x2*>(&n0s[lr + 1][2 * p + 2]) = (f32x2){ n0a, n0b };
        const float sg1a = sigmoidf(a[6][0] + bg1);    // leaf1 gate: bias gbs[:,1]
        const float sg1b = sigmoidf(a[6][1] + bg1);
        n1v[k][0] = sg1a * (a[3][0] + bp2) + (1.f - sg1a) * (a[4][0] + bp3);
        n1v[k][1] = sg1b * (a[3][1] + bp2) + (1.f - sg1b) * (a[4][1] + bp3);
        out1[k][0] = mp0 * (a[0][0] + bmax);
        out1[k][1] = mp1 * (a[0][1] + bmax);
    }
    __syncthreads();

    // ---- stage 2: node gate conv on n0 (stride 1, pad 1) + combine + store ----
    float* oplane = out + (size_t)plane * (OHW * OHW);
#pragma unroll
    for (int k = 0; k < 2; ++k) {
        const int lr = g0 + 8 * k;
        float ag0 = 0.f, ag1 = 0.f, n0c0 = 0.f, n0c1 = 0.f;
#pragma unroll
        for (int dr = 0; dr < 3; ++dr) {
            const float e0  = n0s[lr + dr][2 * p + 1];
            const f32x2 mid = *reinterpret_cast<const f32x2*>(&n0s[lr + dr][2 * p + 2]);
            const float e3  = n0s[lr + dr][2 * p + 4];
            ag0 += e0    * ws[6][3*dr] + mid.x * ws[6][3*dr+1] + mid.y * ws[6][3*dr+2];
            ag1 += mid.x * ws[6][3*dr] + mid.y * ws[6][3*dr+1] + e3    * ws[6][3*dr+2];
            if (dr == 1) { n0c0 = mid.x; n0c1 = mid.y; }
        }
        const float ga = sigmoidf(ag0 + bg2);          // node gate: bias gbs[:,2]
        const float gb = sigmoidf(ag1 + bg2);
        f32x2 rv;
        rv.x = out1[k][0] + n0c0 * ga + n1v[k][0] * (1.f - ga);
        rv.y = out1[k][1] + n0c1 * gb + n1v[k][1] * (1.f - gb);
        __builtin_nontemporal_store(rv,
            reinterpret_cast<f32x2*>(oplane + (r0 + lr) * OHW + 2 * p));
    }
}

extern "C" void kernel_launch(void* const* d_in, const int* in_sizes, int n_in,
                              void* d_out, int out_size, void* d_ws, size_t ws_size,
                              hipStream_t stream) {
    const float* x       = (const float*)d_in[0];
    const float* maxgate = (const float*)d_in[1];
    const float* mb      = (const float*)d_in[2];
    const float* pconvs  = (const float*)d_in[3];
    const float* pbs     = (const float*)d_in[4];
    const float* pgates  = (const float*)d_in[5];
    const float* gbs     = (const float*)d_in[6];
    float* out           = (float*)d_out;

    const int blocks = 16 * 256 * 4;   // one 16-row tile per block
    fused_densenet_kernel<<<blocks, TB, 0, stream>>>(
        x, maxgate, mb, pconvs, pbs, pgates, gbs, out);
}